// Round 6
// baseline (445.770 us; speedup 1.0000x reference)
//
#include <hip/hip_runtime.h>
#include <math.h>

#define N_NODES 50000
#define N_EDGES 800000
#define SCAN_BLK 2048   // elements per scan block (256 threads x 8)
#define LDS_STRIDE 264  // 256 shorts + 8 pad (bank spread)

using short8  = __attribute__((ext_vector_type(8))) short;
using floatx4 = __attribute__((ext_vector_type(4))) float;
using ushortx8 = __attribute__((ext_vector_type(8))) unsigned short;
using uintx4  = __attribute__((ext_vector_type(4))) unsigned;
using uintx2  = __attribute__((ext_vector_type(2))) unsigned;

__device__ inline unsigned short f2bf(float f) {
  unsigned u = __float_as_uint(f);
  u += 0x7fff + ((u >> 16) & 1);   // round-to-nearest-even
  return (unsigned short)(u >> 16);
}

__device__ inline float sigmoidf(float x) { return 1.0f / (1.0f + __expf(-x)); }

// async global->LDS, 16B per lane; per-lane global addr, wave-uniform LDS base
#define GLD16(gaddr, laddr)                                                   \
  __builtin_amdgcn_global_load_lds(                                           \
      (const __attribute__((address_space(1))) unsigned*)(gaddr),             \
      (__attribute__((address_space(3))) unsigned*)(laddr), 16, 0, 0)

// ---------------- prep: edge count + weight pack ----------------
__global__ void prep_kernel(const int* __restrict__ rows, int* __restrict__ counts, int E, int cntB,
                            const float* __restrict__ W1, const float* __restrict__ G1,
                            const float* __restrict__ W2, const float* __restrict__ G2,
                            unsigned short* __restrict__ Wp1, unsigned short* __restrict__ Gp1,
                            unsigned short* __restrict__ Wp2, unsigned short* __restrict__ Gp2) {
  int b = blockIdx.x;
  if (b < cntB) {
    int e = b * 256 + threadIdx.x;
    if (e < E) atomicAdd(&counts[rows[e]], 1);
  } else {
    int idx = (b - cntB) * 256 + threadIdx.x;
    if (idx < 65536) {
      int m = idx >> 8, k = idx & 255;
      Wp1[idx] = f2bf(W1[k * 256 + m]);
    } else if (idx < 131072) {
      int t = idx - 65536; int m = t >> 8, k = t & 255;
      Gp1[t] = f2bf(G1[k * 256 + m]);
    } else if (idx < 163840) {
      int t = idx - 131072; int m = t >> 8, k = t & 255;
      Wp2[t] = f2bf(W2[k * 128 + m]);
    } else {
      int t = idx - 163840; int m = t >> 8, k = t & 255;
      Gp2[t] = f2bf(G2[k * 128 + m]);
    }
  }
}

// ---------------- single-kernel exclusive scan ----------------
__global__ void scan_kernel(const int* __restrict__ counts, int* __restrict__ row_ptr,
                            int* __restrict__ cursor, int N, int E) {
  int tid = threadIdx.x, lane = tid & 63, wv = tid >> 6;
  __shared__ int wpart[4], wsum[4];

  int limit4 = (blockIdx.x * SCAN_BLK) >> 2;
  const int4* c4 = (const int4*)counts;
  int s = 0;
  for (int i = tid; i < limit4; i += 256) {
    int4 v = c4[i];
    s += v.x + v.y + v.z + v.w;
  }
#pragma unroll
  for (int d = 32; d > 0; d >>= 1) s += __shfl_down(s, d, 64);
  if (lane == 0) wpart[wv] = s;
  __syncthreads();
  int blk_off = wpart[0] + wpart[1] + wpart[2] + wpart[3];

  if (blockIdx.x == 0 && tid == 0) row_ptr[N] = E;

  int base = blockIdx.x * SCAN_BLK + tid * 8;
  int v[8];
  int sl = 0;
  if (base < N) {
#pragma unroll
    for (int j = 0; j < 8; ++j) { v[j] = counts[base + j]; sl += v[j]; }
  } else {
#pragma unroll
    for (int j = 0; j < 8; ++j) v[j] = 0;
  }
  int x = sl;
#pragma unroll
  for (int d = 1; d < 64; d <<= 1) {
    int y = __shfl_up(x, d, 64);
    if (lane >= d) x += y;
  }
  if (lane == 63) wsum[wv] = x;
  __syncthreads();
  int woff = 0;
  for (int w = 0; w < wv; ++w) woff += wsum[w];
  int run = blk_off + woff + (x - sl);
  if (base < N) {
#pragma unroll
    for (int j = 0; j < 8; ++j) {
      row_ptr[base + j] = run;
      cursor[base + j] = run;
      run += v[j];
    }
  }
}

// ---------------- work_a: scatter edges || pack x to bf16 ----------------
__global__ __launch_bounds__(256) void work_a_kernel(const int* __restrict__ rows,
                                                     const int* __restrict__ cols,
                                                     const float* __restrict__ vals,
                                                     int* __restrict__ cursor,
                                                     uintx2* __restrict__ colval, int E, int cntB,
                                                     const float* __restrict__ x,
                                                     unsigned short* __restrict__ xp) {
  int b = blockIdx.x;
  if (b < cntB) {
    int e = b * 256 + threadIdx.x;
    if (e >= E) return;
    int r = rows[e];
    int p = atomicAdd(&cursor[r], 1);
    uintx2 cv;
    cv[0] = (unsigned)cols[e];
    cv[1] = __float_as_uint(vals[e]);
    colval[p] = cv;
  } else {
    int idx = (b - cntB) * 256 + threadIdx.x;      // exactly N*256/8 threads
    size_t base = (size_t)idx * 8;
    floatx4 f0 = *(const floatx4*)(x + base);
    floatx4 f1 = *(const floatx4*)(x + base + 4);
    short8 o;
#pragma unroll
    for (int j = 0; j < 4; ++j) { o[j] = (short)f2bf(f0[j]); o[4 + j] = (short)f2bf(f1[j]); }
    *(short8*)(xp + base) = o;
  }
}

// ---------------- phase A core: LDS-staged deep-pipelined gather ----------------
// Half-wave owns one 512B src row; the wave stages 2 edges per global_load_lds instr
// (lanes 0-31 = half A's edge, lanes 32-63 = half B's) into a per-wave LDS double
// buffer (2 bufs x 4 instrs x 1KB). Statically-counted FIFO schedule per group g:
//   issue cv(g+2)[4] -> issue gl(g+1)[4] -> vmcnt(8): gl(g) landed -> consume from LDS
//   -> vmcnt(4): cv(g+2) confirmed for next iter.
// Payload never touches VGPRs -> pipeline depth is LDS-bound, not VGPR-bound:
// ~8 gl-instrs (16 lines each) in flight per wave, ~130 per CU at 16 waves/CU,
// vs ~46 register-pipelined in rounds 0-5. Compiler barriers pin issue order so the
// vmcnt literals stay exact.
__device__ __forceinline__ void gather_stage(const uintx2* __restrict__ colval,
                                             const unsigned short* __restrict__ src,
                                             unsigned* stage_w,   // [2][1024] uints (8KB)
                                             int e0, int n, int lane, int li, float a[8]) {
#pragma unroll
  for (int q = 0; q < 8; ++q) a[q] = 0.f;
  int no = __shfl_xor(n, 32, 64);
  int nmax = n > no ? n : no;
  int G = (nmax + 3) >> 2;          // wave-uniform group count (4 edges/half/group)
  if (G == 0) return;

  auto cidx = [&](int j) {
    int jj = j < n ? j : (n ? n - 1 : 0);
    int ix = e0 + jj;                       // n>0: ix <= e1-1 < E; n==0: clamp below
    return ix < N_EDGES ? ix : N_EDGES - 1;
  };

  // cv(0)
  uintx2 c0 = colval[cidx(0)], c1 = colval[cidx(1)], c2 = colval[cidx(2)], c3 = colval[cidx(3)];
  asm volatile("s_waitcnt vmcnt(0)" ::: "memory");
  unsigned k0 = c0[0], k1 = c1[0], k2 = c2[0], k3 = c3[0];
  float v0 = 0 < n ? __uint_as_float(c0[1]) : 0.f;
  float v1 = 1 < n ? __uint_as_float(c1[1]) : 0.f;
  float v2 = 2 < n ? __uint_as_float(c2[1]) : 0.f;
  float v3 = 3 < n ? __uint_as_float(c3[1]) : 0.f;
  // cv(1), then gl(0) -> buf0   [FIFO: cv1(4), gl0(4)]
  c0 = colval[cidx(4)]; c1 = colval[cidx(5)]; c2 = colval[cidx(6)]; c3 = colval[cidx(7)];
  asm volatile("" ::: "memory");
  GLD16(src + (size_t)k0 * 256 + li * 8, stage_w);
  GLD16(src + (size_t)k1 * 256 + li * 8, stage_w + 256);
  GLD16(src + (size_t)k2 * 256 + li * 8, stage_w + 512);
  GLD16(src + (size_t)k3 * 256 + li * 8, stage_w + 768);
  asm volatile("s_waitcnt vmcnt(4)" ::: "memory");   // cv(1) ready, gl(0) in flight

  for (int g = 0; g < G; ++g) {
    int b = g & 1, nb = b ^ 1;
    // cols/vals of group g+1 (from confirmed regs)
    unsigned nk0 = c0[0], nk1 = c1[0], nk2 = c2[0], nk3 = c3[0];
    int j1 = (g + 1) * 4;
    float w0 = j1 + 0 < n ? __uint_as_float(c0[1]) : 0.f;
    float w1 = j1 + 1 < n ? __uint_as_float(c1[1]) : 0.f;
    float w2 = j1 + 2 < n ? __uint_as_float(c2[1]) : 0.f;
    float w3 = j1 + 3 < n ? __uint_as_float(c3[1]) : 0.f;
    // issue cv(g+2)
    int j2 = (g + 2) * 4;
    c0 = colval[cidx(j2)]; c1 = colval[cidx(j2 + 1)];
    c2 = colval[cidx(j2 + 2)]; c3 = colval[cidx(j2 + 3)];
    asm volatile("" ::: "memory");
    // issue gl(g+1) -> other buffer
    unsigned* db = stage_w + nb * 1024;
    GLD16(src + (size_t)nk0 * 256 + li * 8, db);
    GLD16(src + (size_t)nk1 * 256 + li * 8, db + 256);
    GLD16(src + (size_t)nk2 * 256 + li * 8, db + 512);
    GLD16(src + (size_t)nk3 * 256 + li * 8, db + 768);
    asm volatile("s_waitcnt vmcnt(8)" ::: "memory");  // gl(g) landed in LDS
    // consume group g
    const unsigned* cb = stage_w + b * 1024 + lane * 4;
    uintx4 p0 = *(const uintx4*)(cb);
    uintx4 p1 = *(const uintx4*)(cb + 256);
    uintx4 p2 = *(const uintx4*)(cb + 512);
    uintx4 p3 = *(const uintx4*)(cb + 768);
#pragma unroll
    for (int q = 0; q < 4; ++q) {
      a[2 * q]     += __uint_as_float(p0[q] << 16) * v0;
      a[2 * q + 1] += __uint_as_float(p0[q] & 0xffff0000u) * v0;
    }
#pragma unroll
    for (int q = 0; q < 4; ++q) {
      a[2 * q]     += __uint_as_float(p1[q] << 16) * v1;
      a[2 * q + 1] += __uint_as_float(p1[q] & 0xffff0000u) * v1;
    }
#pragma unroll
    for (int q = 0; q < 4; ++q) {
      a[2 * q]     += __uint_as_float(p2[q] << 16) * v2;
      a[2 * q + 1] += __uint_as_float(p2[q] & 0xffff0000u) * v2;
    }
#pragma unroll
    for (int q = 0; q < 4; ++q) {
      a[2 * q]     += __uint_as_float(p3[q] << 16) * v3;
      a[2 * q + 1] += __uint_as_float(p3[q] & 0xffff0000u) * v3;
    }
    asm volatile("s_waitcnt vmcnt(4)" ::: "memory");  // cv(g+2) confirmed
    v0 = w0; v1 = w1; v2 = w2; v3 = w3;
  }
}

// ---------------- fused1: (A @ x) @ {W1,G1}, relu(sig*S) -> hp bf16 [N][256] ----------------
__global__ __launch_bounds__(512, 4) void fused1_kernel(const int* __restrict__ row_ptr,
                                                        const uintx2* __restrict__ colval,
                                                        const unsigned short* __restrict__ xp,
                                                        const unsigned short* __restrict__ Wp,
                                                        const unsigned short* __restrict__ Gp,
                                                        unsigned short* __restrict__ hp) {
  __shared__ short hlds[16 * LDS_STRIDE];
  __shared__ unsigned stage[8][2][1024];   // 64KB staging
  int lane = threadIdx.x & 63;
  int wid = threadIdx.x >> 6;
  int half = lane >> 5, li = lane & 31;
  int r0 = blockIdx.x * 16;
  int lrow = wid * 2 + half;
  int r = r0 + lrow;

  // ---- phase A ----
  int e0 = row_ptr[r], e1 = row_ptr[r + 1];
  float a[8];
  gather_stage(colval, xp, &stage[wid][0][0], e0, e1 - e0, lane, li, a);
  ushortx8 o;
#pragma unroll
  for (int q = 0; q < 8; ++q) o[q] = f2bf(a[q]);
  *(ushortx8*)(&hlds[lrow * LDS_STRIDE + li * 8]) = o;
  __syncthreads();

  // ---- phase B: 16x256 @ 256x256 dual GEMM, relu(sig*S) epilogue ----
  constexpr int K = 256;
  int quad = lane >> 4, lr = lane & 15;
  int t0 = wid * 2;
  const short* Wb[2];
  const short* Gb[2];
#pragma unroll
  for (int t = 0; t < 2; ++t) {
    size_t boff = (size_t)(t0 + t) * 16 * K + (size_t)lr * K + quad * 8;
    Wb[t] = (const short*)Wp + boff;
    Gb[t] = (const short*)Gp + boff;
  }
  const short* Abase = &hlds[lr * LDS_STRIDE + quad * 8];

  floatx4 zero = {0.f, 0.f, 0.f, 0.f};
  floatx4 accS[2] = {zero, zero}, accG[2] = {zero, zero};
#pragma unroll
  for (int kc = 0; kc < 8; ++kc) {
    short8 av = *(const short8*)(Abase + kc * 32);
#pragma unroll
    for (int t = 0; t < 2; ++t) {
      short8 bw = *(const short8*)(Wb[t] + kc * 32);
      short8 bg = *(const short8*)(Gb[t] + kc * 32);
      accS[t] = __builtin_amdgcn_mfma_f32_16x16x32_bf16(av, bw, accS[t], 0, 0, 0);
      accG[t] = __builtin_amdgcn_mfma_f32_16x16x32_bf16(av, bg, accG[t], 0, 0, 0);
    }
  }
#pragma unroll
  for (int t = 0; t < 2; ++t)
#pragma unroll
    for (int gg = 0; gg < 4; ++gg) {
      int row = r0 + quad * 4 + gg;
      float h = sigmoidf(accG[t][gg]) * accS[t][gg];
      h = fmaxf(h, 0.f);
      hp[(size_t)row * 256 + (t0 + t) * 16 + lr] = f2bf(h);
    }
}

// ---------------- fused2: (A @ h) @ {W2,G2}, sig*S -> out f32 [N][128] ----------------
__global__ __launch_bounds__(512, 4) void fused2_kernel(const int* __restrict__ row_ptr,
                                                        const uintx2* __restrict__ colval,
                                                        const unsigned short* __restrict__ hp,
                                                        const unsigned short* __restrict__ Wp,
                                                        const unsigned short* __restrict__ Gp,
                                                        float* __restrict__ out) {
  __shared__ short hlds[16 * LDS_STRIDE];
  __shared__ unsigned stage[8][2][1024];
  int lane = threadIdx.x & 63;
  int wid = threadIdx.x >> 6;
  int half = lane >> 5, li = lane & 31;
  int r0 = blockIdx.x * 16;
  int lrow = wid * 2 + half;
  int r = r0 + lrow;

  // ---- phase A ----
  int e0 = row_ptr[r], e1 = row_ptr[r + 1];
  float a[8];
  gather_stage(colval, hp, &stage[wid][0][0], e0, e1 - e0, lane, li, a);
  ushortx8 o;
#pragma unroll
  for (int q = 0; q < 8; ++q) o[q] = f2bf(a[q]);
  *(ushortx8*)(&hlds[lrow * LDS_STRIDE + li * 8]) = o;
  __syncthreads();

  // ---- phase B: 16x256 @ 256x128 dual GEMM, sig(G)*S epilogue (f32 out) ----
  constexpr int K = 256;
  int quad = lane >> 4, lr = lane & 15;
  int t = wid;  // 8 waves x 1 tile = 128 cols
  const short* Wb = (const short*)Wp + (size_t)t * 16 * K + (size_t)lr * K + quad * 8;
  const short* Gb = (const short*)Gp + (size_t)t * 16 * K + (size_t)lr * K + quad * 8;
  const short* Abase = &hlds[lr * LDS_STRIDE + quad * 8];

  floatx4 zero = {0.f, 0.f, 0.f, 0.f};
  floatx4 accS = zero, accG = zero;
#pragma unroll
  for (int kc = 0; kc < 8; ++kc) {
    short8 av = *(const short8*)(Abase + kc * 32);
    short8 bw = *(const short8*)(Wb + kc * 32);
    short8 bg = *(const short8*)(Gb + kc * 32);
    accS = __builtin_amdgcn_mfma_f32_16x16x32_bf16(av, bw, accS, 0, 0, 0);
    accG = __builtin_amdgcn_mfma_f32_16x16x32_bf16(av, bg, accG, 0, 0, 0);
  }
#pragma unroll
  for (int gg = 0; gg < 4; ++gg) {
    int row = r0 + quad * 4 + gg;
    out[(size_t)row * 128 + t * 16 + lr] = sigmoidf(accG[gg]) * accS[gg];
  }
}

// ---------------- launch ----------------

extern "C" void kernel_launch(void* const* d_in, const int* in_sizes, int n_in,
                              void* d_out, int out_size, void* d_ws, size_t ws_size,
                              hipStream_t stream) {
  const float* x    = (const float*)d_in[0];
  const int*   rows = (const int*)d_in[1];
  const int*   cols = (const int*)d_in[2];
  const float* vals = (const float*)d_in[3];
  const float* W1   = (const float*)d_in[4];
  const float* G1   = (const float*)d_in[5];
  const float* W2   = (const float*)d_in[6];
  const float* G2   = (const float*)d_in[7];

  const int N = N_NODES, E = N_EDGES;
  char* ws = (char*)d_ws;
  size_t off = 0;
  auto alloc = [&](size_t bytes) -> char* {
    off = (off + 255) & ~(size_t)255;
    char* p = ws + off;
    off += bytes;
    return p;
  };
  int*   counts  = (int*)alloc((size_t)N * 4);
  int*   row_ptr = (int*)alloc((size_t)(N + 1) * 4);
  int*   cursor  = (int*)alloc((size_t)N * 4);
  uintx2* colval = (uintx2*)alloc((size_t)E * 8);
  unsigned short* Wp1 = (unsigned short*)alloc(256 * 256 * 2);
  unsigned short* Gp1 = (unsigned short*)alloc(256 * 256 * 2);
  unsigned short* Wp2 = (unsigned short*)alloc(256 * 128 * 2);
  unsigned short* Gp2 = (unsigned short*)alloc(256 * 128 * 2);
  unsigned short* xp  = (unsigned short*)alloc((size_t)N * 256 * 2);  // bf16 x
  unsigned short* hp  = (unsigned short*)alloc((size_t)N * 256 * 2);  // bf16 h

  (void)hipMemsetAsync(counts, 0, (size_t)N * 4, stream);

  int cntB = (E + 255) / 256;           // 3125
  prep_kernel<<<cntB + 768, 256, 0, stream>>>(rows, counts, E, cntB,
                                              W1, G1, W2, G2, Wp1, Gp1, Wp2, Gp2);

  int scanB = (N + SCAN_BLK - 1) / SCAN_BLK;   // 25
  scan_kernel<<<scanB, 256, 0, stream>>>(counts, row_ptr, cursor, N, E);

  // scatter || x-pack
  int packB = (N * 256 / 8) / 256;      // 6250
  work_a_kernel<<<cntB + packB, 256, 0, stream>>>(rows, cols, vals, cursor, colval, E, cntB, x, xp);

  // layer 1: (A @ x) @ {W1,G1}, relu(sig*S) -> hp
  fused1_kernel<<<N / 16, 512, 0, stream>>>(row_ptr, colval, xp, Wp1, Gp1, hp);

  // layer 2: (A @ h) @ {W2,G2}, sig*S -> out
  fused2_kernel<<<N / 16, 512, 0, stream>>>(row_ptr, colval, hp, Wp2, Gp2, (float*)d_out);
}

// Round 7
// 428.650 us; speedup vs baseline: 1.0399x; 1.0399x over previous
//
#include <hip/hip_runtime.h>
#include <math.h>

#define N_NODES 50000
#define N_EDGES 800000
#define SCAN_BLK 2048   // elements per scan block (256 threads x 8)
#define LDS_STRIDE 264  // 256 shorts + 8 pad (bank spread)

using short8  = __attribute__((ext_vector_type(8))) short;
using floatx4 = __attribute__((ext_vector_type(4))) float;
using ushortx8 = __attribute__((ext_vector_type(8))) unsigned short;
using uintx4  = __attribute__((ext_vector_type(4))) unsigned;
using uintx2  = __attribute__((ext_vector_type(2))) unsigned;

__device__ inline unsigned short f2bf(float f) {
  unsigned u = __float_as_uint(f);
  u += 0x7fff + ((u >> 16) & 1);   // round-to-nearest-even
  return (unsigned short)(u >> 16);
}

__device__ inline float sigmoidf(float x) { return 1.0f / (1.0f + __expf(-x)); }

// ---------------- prep: edge count || weight pack || x pack ----------------
// x-pack has no dependency on the scan, so it lives here (overlapped with the
// count atomics) instead of serializing after the scan in work_a.
__global__ void prep_kernel(const int* __restrict__ rows, int* __restrict__ counts, int E, int cntB,
                            const float* __restrict__ W1, const float* __restrict__ G1,
                            const float* __restrict__ W2, const float* __restrict__ G2,
                            unsigned short* __restrict__ Wp1, unsigned short* __restrict__ Gp1,
                            unsigned short* __restrict__ Wp2, unsigned short* __restrict__ Gp2,
                            const float* __restrict__ x, unsigned short* __restrict__ xp) {
  int b = blockIdx.x;
  if (b < cntB) {
    int e = b * 256 + threadIdx.x;
    if (e < E) atomicAdd(&counts[rows[e]], 1);
  } else if (b < cntB + 768) {
    int idx = (b - cntB) * 256 + threadIdx.x;
    if (idx < 65536) {
      int m = idx >> 8, k = idx & 255;
      Wp1[idx] = f2bf(W1[k * 256 + m]);
    } else if (idx < 131072) {
      int t = idx - 65536; int m = t >> 8, k = t & 255;
      Gp1[t] = f2bf(G1[k * 256 + m]);
    } else if (idx < 163840) {
      int t = idx - 131072; int m = t >> 8, k = t & 255;
      Wp2[t] = f2bf(W2[k * 128 + m]);
    } else {
      int t = idx - 163840; int m = t >> 8, k = t & 255;
      Gp2[t] = f2bf(G2[k * 128 + m]);
    }
  } else {
    int idx = (b - cntB - 768) * 256 + threadIdx.x;   // exactly N*256/8 threads
    size_t base = (size_t)idx * 8;
    floatx4 f0 = *(const floatx4*)(x + base);
    floatx4 f1 = *(const floatx4*)(x + base + 4);
    short8 o;
#pragma unroll
    for (int j = 0; j < 4; ++j) { o[j] = (short)f2bf(f0[j]); o[4 + j] = (short)f2bf(f1[j]); }
    *(short8*)(xp + base) = o;
  }
}

// ---------------- single-kernel exclusive scan ----------------
__global__ void scan_kernel(const int* __restrict__ counts, int* __restrict__ row_ptr,
                            int* __restrict__ cursor, int N, int E) {
  int tid = threadIdx.x, lane = tid & 63, wv = tid >> 6;
  __shared__ int wpart[4], wsum[4];

  int limit4 = (blockIdx.x * SCAN_BLK) >> 2;
  const int4* c4 = (const int4*)counts;
  int s = 0;
  for (int i = tid; i < limit4; i += 256) {
    int4 v = c4[i];
    s += v.x + v.y + v.z + v.w;
  }
#pragma unroll
  for (int d = 32; d > 0; d >>= 1) s += __shfl_down(s, d, 64);
  if (lane == 0) wpart[wv] = s;
  __syncthreads();
  int blk_off = wpart[0] + wpart[1] + wpart[2] + wpart[3];

  if (blockIdx.x == 0 && tid == 0) row_ptr[N] = E;

  int base = blockIdx.x * SCAN_BLK + tid * 8;
  int v[8];
  int sl = 0;
  if (base < N) {
#pragma unroll
    for (int j = 0; j < 8; ++j) { v[j] = counts[base + j]; sl += v[j]; }
  } else {
#pragma unroll
    for (int j = 0; j < 8; ++j) v[j] = 0;
  }
  int x = sl;
#pragma unroll
  for (int d = 1; d < 64; d <<= 1) {
    int y = __shfl_up(x, d, 64);
    if (lane >= d) x += y;
  }
  if (lane == 63) wsum[wv] = x;
  __syncthreads();
  int woff = 0;
  for (int w = 0; w < wv; ++w) woff += wsum[w];
  int run = blk_off + woff + (x - sl);
  if (base < N) {
#pragma unroll
    for (int j = 0; j < 8; ++j) {
      row_ptr[base + j] = run;
      cursor[base + j] = run;
      run += v[j];
    }
  }
}

// ---------------- scatter: edges into packed 8B {col,val} CSR records ----------------
__global__ __launch_bounds__(256) void scatter_kernel(const int* __restrict__ rows,
                                                      const int* __restrict__ cols,
                                                      const float* __restrict__ vals,
                                                      int* __restrict__ cursor,
                                                      uintx2* __restrict__ colval, int E) {
  int e = blockIdx.x * 256 + threadIdx.x;
  if (e >= E) return;
  int r = rows[e];
  int p = atomicAdd(&cursor[r], 1);
  uintx2 cv;
  cv[0] = (unsigned)cols[e];
  cv[1] = __float_as_uint(vals[e]);
  colval[p] = cv;
}

// ---------------- phase A core: row-per-half-wave gather, vectorized colval ----------------
// Half-wave (32 lanes x 16B = 512B) owns one src row. Per 4-edge group: TWO uintx4
// colval loads (each carries 2 edge records -> halves the colval instruction AND
// segment count vs 4x8B), then four named 16B/lane row gathers in flight, then consume.
// This round's experiment: does the ~5.5 segments/ns device-wide law (measured across
// rounds 0-6) also count these small uniform loads? If yes, -0.5 seg/edge => big win.
__device__ __forceinline__ void gather_row(const uintx2* __restrict__ colval,
                                           const unsigned short* __restrict__ src,
                                           int e0, int e1, int li, float a[8]) {
#pragma unroll
  for (int q = 0; q < 8; ++q) a[q] = 0.f;
  int n = e1 - e0;
  const uintx2* cv = colval + e0;
  int e = 0;
  for (; e + 4 <= n; e += 4) {
    uintx4 c01 = *(const uintx4*)(cv + e);       // records e, e+1   (16B @ 8B align: legal)
    uintx4 c23 = *(const uintx4*)(cv + e + 2);   // records e+2, e+3
    uintx4 p0 = ((const uintx4*)(src + (size_t)c01[0] * 256))[li];
    uintx4 p1 = ((const uintx4*)(src + (size_t)c01[2] * 256))[li];
    uintx4 p2 = ((const uintx4*)(src + (size_t)c23[0] * 256))[li];
    uintx4 p3 = ((const uintx4*)(src + (size_t)c23[2] * 256))[li];
    float v0 = __uint_as_float(c01[1]), v1 = __uint_as_float(c01[3]);
    float v2 = __uint_as_float(c23[1]), v3 = __uint_as_float(c23[3]);
#pragma unroll
    for (int q = 0; q < 4; ++q) {
      a[2 * q]     += __uint_as_float(p0[q] << 16) * v0;
      a[2 * q + 1] += __uint_as_float(p0[q] & 0xffff0000u) * v0;
    }
#pragma unroll
    for (int q = 0; q < 4; ++q) {
      a[2 * q]     += __uint_as_float(p1[q] << 16) * v1;
      a[2 * q + 1] += __uint_as_float(p1[q] & 0xffff0000u) * v1;
    }
#pragma unroll
    for (int q = 0; q < 4; ++q) {
      a[2 * q]     += __uint_as_float(p2[q] << 16) * v2;
      a[2 * q + 1] += __uint_as_float(p2[q] & 0xffff0000u) * v2;
    }
#pragma unroll
    for (int q = 0; q < 4; ++q) {
      a[2 * q]     += __uint_as_float(p3[q] << 16) * v3;
      a[2 * q + 1] += __uint_as_float(p3[q] & 0xffff0000u) * v3;
    }
  }
  for (; e < n; ++e) {
    uintx2 c = cv[e];
    uintx4 p = ((const uintx4*)(src + (size_t)c[0] * 256))[li];
    float v = __uint_as_float(c[1]);
#pragma unroll
    for (int q = 0; q < 4; ++q) {
      a[2 * q]     += __uint_as_float(p[q] << 16) * v;
      a[2 * q + 1] += __uint_as_float(p[q] & 0xffff0000u) * v;
    }
  }
}

// ---------------- fused1: (A @ x) @ {W1,G1}, relu(sig*S) -> hp bf16 [N][256] ----------------
// 512 threads = 8 waves = 16 half-waves = 16 rows gathered in parallel, then
// 16x256 @ 256x256 dual GEMM (2 N-tiles per wave).
__global__ __launch_bounds__(512) void fused1_kernel(const int* __restrict__ row_ptr,
                                                     const uintx2* __restrict__ colval,
                                                     const unsigned short* __restrict__ xp,
                                                     const unsigned short* __restrict__ Wp,
                                                     const unsigned short* __restrict__ Gp,
                                                     unsigned short* __restrict__ hp) {
  __shared__ short hlds[16 * LDS_STRIDE];
  int lane = threadIdx.x & 63;
  int wid = threadIdx.x >> 6;
  int half = lane >> 5, li = lane & 31;
  int r0 = blockIdx.x * 16;
  int lrow = wid * 2 + half;
  int r = r0 + lrow;

  // ---- phase A ----
  int e0 = row_ptr[r], e1 = row_ptr[r + 1];
  float a[8];
  gather_row(colval, xp, e0, e1, li, a);
  ushortx8 o;
#pragma unroll
  for (int q = 0; q < 8; ++q) o[q] = f2bf(a[q]);
  *(ushortx8*)(&hlds[lrow * LDS_STRIDE + li * 8]) = o;
  __syncthreads();

  // ---- phase B: 16x256 @ 256x256 dual GEMM, relu(sig*S) epilogue ----
  constexpr int K = 256;
  int quad = lane >> 4, lr = lane & 15;
  int t0 = wid * 2;
  const short* Wb[2];
  const short* Gb[2];
#pragma unroll
  for (int t = 0; t < 2; ++t) {
    size_t boff = (size_t)(t0 + t) * 16 * K + (size_t)lr * K + quad * 8;
    Wb[t] = (const short*)Wp + boff;
    Gb[t] = (const short*)Gp + boff;
  }
  const short* Abase = &hlds[lr * LDS_STRIDE + quad * 8];

  floatx4 zero = {0.f, 0.f, 0.f, 0.f};
  floatx4 accS[2] = {zero, zero}, accG[2] = {zero, zero};
#pragma unroll
  for (int kc = 0; kc < 8; ++kc) {
    short8 av = *(const short8*)(Abase + kc * 32);
#pragma unroll
    for (int t = 0; t < 2; ++t) {
      short8 bw = *(const short8*)(Wb[t] + kc * 32);
      short8 bg = *(const short8*)(Gb[t] + kc * 32);
      accS[t] = __builtin_amdgcn_mfma_f32_16x16x32_bf16(av, bw, accS[t], 0, 0, 0);
      accG[t] = __builtin_amdgcn_mfma_f32_16x16x32_bf16(av, bg, accG[t], 0, 0, 0);
    }
  }
#pragma unroll
  for (int t = 0; t < 2; ++t)
#pragma unroll
    for (int gg = 0; gg < 4; ++gg) {
      int row = r0 + quad * 4 + gg;
      float h = sigmoidf(accG[t][gg]) * accS[t][gg];
      h = fmaxf(h, 0.f);
      hp[(size_t)row * 256 + (t0 + t) * 16 + lr] = f2bf(h);
    }
}

// ---------------- fused2: (A @ h) @ {W2,G2}, sig*S -> out f32 [N][128] ----------------
__global__ __launch_bounds__(512) void fused2_kernel(const int* __restrict__ row_ptr,
                                                     const uintx2* __restrict__ colval,
                                                     const unsigned short* __restrict__ hp,
                                                     const unsigned short* __restrict__ Wp,
                                                     const unsigned short* __restrict__ Gp,
                                                     float* __restrict__ out) {
  __shared__ short hlds[16 * LDS_STRIDE];
  int lane = threadIdx.x & 63;
  int wid = threadIdx.x >> 6;
  int half = lane >> 5, li = lane & 31;
  int r0 = blockIdx.x * 16;
  int lrow = wid * 2 + half;
  int r = r0 + lrow;

  // ---- phase A ----
  int e0 = row_ptr[r], e1 = row_ptr[r + 1];
  float a[8];
  gather_row(colval, hp, e0, e1, li, a);
  ushortx8 o;
#pragma unroll
  for (int q = 0; q < 8; ++q) o[q] = f2bf(a[q]);
  *(ushortx8*)(&hlds[lrow * LDS_STRIDE + li * 8]) = o;
  __syncthreads();

  // ---- phase B: 16x256 @ 256x128 dual GEMM, sig(G)*S epilogue (f32 out) ----
  constexpr int K = 256;
  int quad = lane >> 4, lr = lane & 15;
  int t = wid;  // 8 waves x 1 tile = 128 cols
  const short* Wb = (const short*)Wp + (size_t)t * 16 * K + (size_t)lr * K + quad * 8;
  const short* Gb = (const short*)Gp + (size_t)t * 16 * K + (size_t)lr * K + quad * 8;
  const short* Abase = &hlds[lr * LDS_STRIDE + quad * 8];

  floatx4 zero = {0.f, 0.f, 0.f, 0.f};
  floatx4 accS = zero, accG = zero;
#pragma unroll
  for (int kc = 0; kc < 8; ++kc) {
    short8 av = *(const short8*)(Abase + kc * 32);
    short8 bw = *(const short8*)(Wb + kc * 32);
    short8 bg = *(const short8*)(Gb + kc * 32);
    accS = __builtin_amdgcn_mfma_f32_16x16x32_bf16(av, bw, accS, 0, 0, 0);
    accG = __builtin_amdgcn_mfma_f32_16x16x32_bf16(av, bg, accG, 0, 0, 0);
  }
#pragma unroll
  for (int gg = 0; gg < 4; ++gg) {
    int row = r0 + quad * 4 + gg;
    out[(size_t)row * 128 + t * 16 + lr] = sigmoidf(accG[gg]) * accS[gg];
  }
}

// ---------------- launch ----------------

extern "C" void kernel_launch(void* const* d_in, const int* in_sizes, int n_in,
                              void* d_out, int out_size, void* d_ws, size_t ws_size,
                              hipStream_t stream) {
  const float* x    = (const float*)d_in[0];
  const int*   rows = (const int*)d_in[1];
  const int*   cols = (const int*)d_in[2];
  const float* vals = (const float*)d_in[3];
  const float* W1   = (const float*)d_in[4];
  const float* G1   = (const float*)d_in[5];
  const float* W2   = (const float*)d_in[6];
  const float* G2   = (const float*)d_in[7];

  const int N = N_NODES, E = N_EDGES;
  char* ws = (char*)d_ws;
  size_t off = 0;
  auto alloc = [&](size_t bytes) -> char* {
    off = (off + 255) & ~(size_t)255;
    char* p = ws + off;
    off += bytes;
    return p;
  };
  int*   counts  = (int*)alloc((size_t)N * 4);
  int*   row_ptr = (int*)alloc((size_t)(N + 1) * 4);
  int*   cursor  = (int*)alloc((size_t)N * 4);
  uintx2* colval = (uintx2*)alloc((size_t)E * 8);
  unsigned short* Wp1 = (unsigned short*)alloc(256 * 256 * 2);
  unsigned short* Gp1 = (unsigned short*)alloc(256 * 256 * 2);
  unsigned short* Wp2 = (unsigned short*)alloc(256 * 128 * 2);
  unsigned short* Gp2 = (unsigned short*)alloc(256 * 128 * 2);
  unsigned short* xp  = (unsigned short*)alloc((size_t)N * 256 * 2);  // bf16 x
  unsigned short* hp  = (unsigned short*)alloc((size_t)N * 256 * 2);  // bf16 h

  (void)hipMemsetAsync(counts, 0, (size_t)N * 4, stream);

  int cntB = (E + 255) / 256;           // 3125
  int packB = (N * 256 / 8) / 256;      // 6250
  prep_kernel<<<cntB + 768 + packB, 256, 0, stream>>>(rows, counts, E, cntB,
                                                      W1, G1, W2, G2, Wp1, Gp1, Wp2, Gp2, x, xp);

  int scanB = (N + SCAN_BLK - 1) / SCAN_BLK;   // 25
  scan_kernel<<<scanB, 256, 0, stream>>>(counts, row_ptr, cursor, N, E);

  scatter_kernel<<<cntB, 256, 0, stream>>>(rows, cols, vals, cursor, colval, E);

  // layer 1: (A @ x) @ {W1,G1}, relu(sig*S) -> hp
  fused1_kernel<<<N / 16, 512, 0, stream>>>(row_ptr, colval, xp, Wp1, Gp1, hp);

  // layer 2: (A @ h) @ {W2,G2}, sig*S -> out
  fused2_kernel<<<N / 16, 512, 0, stream>>>(row_ptr, colval, hp, Wp2, Gp2, (float*)d_out);
}